// Round 1
// baseline (2244.056 us; speedup 1.0000x reference)
//
#include <hip/hip_runtime.h>

#define NN 16384      // atoms
#define DIM 64        // hidden dim
#define NMOL 256      // molecules
#define KSPLIT 4      // split-K factor for spmm

typedef __bf16 bf16x8 __attribute__((ext_vector_type(8)));
typedef short short8 __attribute__((ext_vector_type(8)));
typedef float floatx4 __attribute__((ext_vector_type(4)));

// fp32 -> bf16 bits, round-to-nearest-even
static __device__ __forceinline__ unsigned short f2bf(float f) {
  unsigned int u = __float_as_uint(f);
  u += 0x7fffu + ((u >> 16) & 1u);
  return (unsigned short)(u >> 16);
}

// ---------------- embedding gather: h[i][c] = emb[fp[i]][c] ----------------
__global__ void k_embed(float* __restrict__ h, const int* __restrict__ fp,
                        const float* __restrict__ emb) {
  int idx = blockIdx.x * 256 + threadIdx.x;     // over NN*DIM
  int i = idx >> 6, c = idx & 63;
  h[idx] = emb[fp[i] * DIM + c];
}

// ------- x = h + sum(parts); h = relu(x @ W + b); also hT = bf16(h)^T -------
// block: 256 threads = 16 rows x 16 col-groups (4 cols each); grid NN/16
__global__ __launch_bounds__(256)
void k_dense(float* __restrict__ h, unsigned short* __restrict__ hT,
             const float* __restrict__ parts, int nparts,
             const float* __restrict__ W, const float* __restrict__ b) {
  __shared__ float Ws[DIM * DIM];   // 16 KiB
  __shared__ float xs[16 * DIM];    // 4 KiB
  const int tid = threadIdx.x;
  const int row0 = blockIdx.x * 16;
#pragma unroll
  for (int i = 0; i < 16; ++i) Ws[i * 256 + tid] = W[i * 256 + tid];
#pragma unroll
  for (int i = 0; i < 4; ++i) {
    int off = row0 * DIM + i * 256 + tid;
    float v = h[off];
    for (int s = 0; s < nparts; ++s) v += parts[(size_t)s * (NN * DIM) + off];
    xs[i * 256 + tid] = v;
  }
  __syncthreads();
  const int rl = tid >> 4;          // row within block, 0..15
  const int c4 = (tid & 15) * 4;    // first of 4 output cols
  float4 bv = *(const float4*)(b + c4);
  float a0 = bv.x, a1 = bv.y, a2 = bv.z, a3 = bv.w;
#pragma unroll
  for (int k = 0; k < DIM; ++k) {
    float xv = xs[rl * DIM + k];
    float4 wv = *(const float4*)(Ws + k * DIM + c4);
    a0 = fmaf(xv, wv.x, a0);
    a1 = fmaf(xv, wv.y, a1);
    a2 = fmaf(xv, wv.z, a2);
    a3 = fmaf(xv, wv.w, a3);
  }
  a0 = fmaxf(a0, 0.f); a1 = fmaxf(a1, 0.f);
  a2 = fmaxf(a2, 0.f); a3 = fmaxf(a3, 0.f);
  const int row = row0 + rl;
  float4 o = make_float4(a0, a1, a2, a3);
  *(float4*)(h + row * DIM + c4) = o;
  hT[(size_t)(c4 + 0) * NN + row] = f2bf(a0);
  hT[(size_t)(c4 + 1) * NN + row] = f2bf(a1);
  hT[(size_t)(c4 + 2) * NN + row] = f2bf(a2);
  hT[(size_t)(c4 + 3) * NN + row] = f2bf(a3);
}

// ---------- parts[kq] = A[:, kq-slice] @ h[kq-slice, :]  (bf16 MFMA) --------
// grid (NN/64, KSPLIT), block 256 = 4 waves; wave w: rows [bx*64+w*16, +16)
__global__ __launch_bounds__(256)
void k_spmm(float* __restrict__ parts, const unsigned short* __restrict__ hT,
            const float* __restrict__ A) {
  const int tid = threadIdx.x;
  const int w = tid >> 6, lane = tid & 63;
  const int lm = lane & 15, q = lane >> 4;
  const int rowA = blockIdx.x * 64 + w * 16 + lm;   // A row this lane streams
  const int kq = blockIdx.y;
  const float* __restrict__ arow =
      A + (size_t)rowA * NN + kq * (NN / KSPLIT);
  const unsigned short* __restrict__ hTq = hT + kq * (NN / KSPLIT);
  floatx4 acc0 = {0.f, 0.f, 0.f, 0.f};
  floatx4 acc1 = acc0, acc2 = acc0, acc3 = acc0;
  for (int kk = 0; kk < NN / KSPLIT; kk += 32) {
    const int ko = kk + q * 8;
    float4 A0 = *(const float4*)(arow + ko);
    float4 A1 = *(const float4*)(arow + ko + 4);
    short8 as;
    as[0] = (short)f2bf(A0.x); as[1] = (short)f2bf(A0.y);
    as[2] = (short)f2bf(A0.z); as[3] = (short)f2bf(A0.w);
    as[4] = (short)f2bf(A1.x); as[5] = (short)f2bf(A1.y);
    as[6] = (short)f2bf(A1.z); as[7] = (short)f2bf(A1.w);
    bf16x8 av = __builtin_bit_cast(bf16x8, as);
    bf16x8 b0 = __builtin_bit_cast(bf16x8,
        *(const short8*)(hTq + (size_t)(lm +  0) * NN + ko));
    bf16x8 b1 = __builtin_bit_cast(bf16x8,
        *(const short8*)(hTq + (size_t)(lm + 16) * NN + ko));
    bf16x8 b2 = __builtin_bit_cast(bf16x8,
        *(const short8*)(hTq + (size_t)(lm + 32) * NN + ko));
    bf16x8 b3 = __builtin_bit_cast(bf16x8,
        *(const short8*)(hTq + (size_t)(lm + 48) * NN + ko));
    acc0 = __builtin_amdgcn_mfma_f32_16x16x32_bf16(av, b0, acc0, 0, 0, 0);
    acc1 = __builtin_amdgcn_mfma_f32_16x16x32_bf16(av, b1, acc1, 0, 0, 0);
    acc2 = __builtin_amdgcn_mfma_f32_16x16x32_bf16(av, b2, acc2, 0, 0, 0);
    acc3 = __builtin_amdgcn_mfma_f32_16x16x32_bf16(av, b3, acc3, 0, 0, 0);
  }
  // C/D layout (verified m89/m91): col = lane&15, row = (lane>>4)*4 + reg
  float* prt = parts + (size_t)kq * (NN * DIM);
  const int orow = blockIdx.x * 64 + w * 16 + q * 4;
#pragma unroll
  for (int r = 0; r < 4; ++r) {
    prt[(orow + r) * DIM + lm +  0] = acc0[r];
    prt[(orow + r) * DIM + lm + 16] = acc1[r];
    prt[(orow + r) * DIM + lm + 32] = acc2[r];
    prt[(orow + r) * DIM + lm + 48] = acc3[r];
  }
}

// ------- out[m][c] = sum over atoms of molecule m of (h + sum parts) --------
// one wave per molecule; segment_ids sorted -> binary search bounds
__global__ void k_seg(float* __restrict__ out, const float* __restrict__ h,
                      const float* __restrict__ parts,
                      const int* __restrict__ seg) {
  const int m = blockIdx.x;
  const int c = threadIdx.x;  // 0..63
  int l = 0, r = NN;
  while (l < r) { int mid = (l + r) >> 1; if (seg[mid] < m) l = mid + 1; else r = mid; }
  const int lo = l;
  r = NN;
  while (l < r) { int mid = (l + r) >> 1; if (seg[mid] < m + 1) l = mid + 1; else r = mid; }
  const int hi = l;
  float acc = 0.f;
  for (int i = lo; i < hi; ++i) {
    int off = i * DIM + c;
    float v = h[off];
#pragma unroll
    for (int s = 0; s < KSPLIT; ++s) v += parts[(size_t)s * (NN * DIM) + off];
    acc += v;
  }
  out[m * DIM + c] = acc;
}

extern "C" void kernel_launch(void* const* d_in, const int* in_sizes, int n_in,
                              void* d_out, int out_size, void* d_ws, size_t ws_size,
                              hipStream_t stream) {
  const int*   fp  = (const int*)d_in[0];
  const float* A   = (const float*)d_in[1];
  const int*   seg = (const int*)d_in[2];
  const float* emb = (const float*)d_in[3];
  const float* W   = (const float*)d_in[4];
  const float* b   = (const float*)d_in[5];
  float* out = (float*)d_out;

  char* ws = (char*)d_ws;
  float* h = (float*)ws;                                           // 4 MiB
  unsigned short* hT = (unsigned short*)(ws + (size_t)NN * DIM * 4); // 2 MiB
  float* parts = (float*)(ws + (size_t)NN * DIM * 6);              // 16 MiB

  k_embed<<<NN * DIM / 256, 256, 0, stream>>>(h, fp, emb);
  for (int l = 0; l < 3; ++l) {
    k_dense<<<NN / 16, 256, 0, stream>>>(h, hT, parts, (l == 0) ? 0 : KSPLIT,
                                         W + l * DIM * DIM, b + l * DIM);
    k_spmm<<<dim3(NN / 64, KSPLIT), 256, 0, stream>>>(parts, hT, A);
  }
  k_seg<<<NMOL, 64, 0, stream>>>(out, h, parts, seg);
}